// Round 13
// baseline (348.828 us; speedup 1.0000x reference)
//
#include <hip/hip_runtime.h>
#include <hip/hip_bf16.h>
#include <math.h>

#define Bn  2
#define Sn  2048
#define Dn  1024
#define Hn  16
#define HDn 64

typedef __attribute__((ext_vector_type(8))) short bf16x8;
typedef __attribute__((ext_vector_type(4))) short bf16x4;
typedef __attribute__((ext_vector_type(4))) float f32x4;

#define LOG2E 1.44269504088896340736f

// raw v_exp_f32 (2^x). __exp2f is NOT a HIP intrinsic (glibc macro collision).
__device__ __forceinline__ float fexp2(float x) {
    return __builtin_amdgcn_exp2f(x);
}

// packed f32x2 -> bf16x2 converts (v_cvt_pk_bf16_f32 on gfx950)
__device__ __forceinline__ uint2 pack4bf(float a, float b, float c, float d) {
    union { __hip_bfloat162 h2[2]; uint2 u; } p;
    p.h2[0] = __float22bfloat162_rn(make_float2(a, b));
    p.h2[1] = __float22bfloat162_rn(make_float2(c, d));
    return p.u;
}

__device__ __forceinline__ bf16x4 pack4bfv(float a, float b, float c, float d) {
    union { __hip_bfloat162 h2[2]; bf16x4 v; } p;
    p.h2[0] = __float22bfloat162_rn(make_float2(a, b));
    p.h2[1] = __float22bfloat162_rn(make_float2(c, d));
    return p.v;
}

// async global->LDS, 16B per lane. lbase must be wave-uniform; g is per-lane.
__device__ __forceinline__ void g2l16(const void* g, void* lbase) {
    __builtin_amdgcn_global_load_lds(
        (const __attribute__((address_space(1))) void*)g,
        (__attribute__((address_space(3))) void*)lbase, 16, 0, 0);
}

// ---------------------------------------------------------------------------
// Fused prep: casts x + 4 weights to bf16, and builds the RoPE cos/sin table.
// ---------------------------------------------------------------------------
__global__ __launch_bounds__(256) void prep_kernel(
    const float* __restrict__ x,
    const float* __restrict__ Wq, const float* __restrict__ Wk,
    const float* __restrict__ Wv, const float* __restrict__ Wo,
    __hip_bfloat16* __restrict__ Xb,
    __hip_bfloat16* __restrict__ Wqb, __hip_bfloat16* __restrict__ Wkb,
    __hip_bfloat16* __restrict__ Wvb, __hip_bfloat16* __restrict__ Wob,
    float2* __restrict__ CS)
{
    const int bx = blockIdx.x, tid = threadIdx.x;
    if (bx < 4096) {
        const size_t i = (size_t)bx * 1024 + tid * 4;
        float4 v = *(const float4*)(x + i);
        *(uint2*)(Xb + i) = pack4bf(v.x, v.y, v.z, v.w);
    } else if (bx < 8192) {
        const int r = bx - 4096;
        const int which = r >> 10;
        const size_t i = (size_t)(r & 1023) * 1024 + tid * 4;
        const float* s = (which == 0) ? Wq : (which == 1) ? Wk : (which == 2) ? Wv : Wo;
        __hip_bfloat16* d = (which == 0) ? Wqb : (which == 1) ? Wkb : (which == 2) ? Wvb : Wob;
        float4 v = *(const float4*)(s + i);
        *(uint2*)(d + i) = pack4bf(v.x, v.y, v.z, v.w);
    } else {
        const float NEG_L2C = -0.41524101186092033f;   // -log2(10000)/32
        const int idx = ((bx - 8192) * 256 + tid) * 2;  // even
        const int s = idx >> 6, d0 = idx & 63;
        const float sf = (float)s;
        const float f0 = exp2f((float)(d0 & 31) * NEG_L2C);
        const float f1 = exp2f((float)((d0 + 1) & 31) * NEG_L2C);
        *(float4*)(&CS[(size_t)s * 64 + d0]) =
            make_float4(__cosf(sf * f0), __sinf(sf * f0),
                        __cosf(sf * f1), __sinf(sf * f1));
    }
}

// ---------------------------------------------------------------------------
// Fused Q/K/V projection GEMM. XCD-swizzled 1-D grid (768 blocks, 3/CU).
// 128x128 tile, BK=64, 32 KB LDS, 2x2 wave grid.
// ---------------------------------------------------------------------------
__global__ __launch_bounds__(256) void qkv_proj(
    const __hip_bfloat16* __restrict__ X,
    const __hip_bfloat16* __restrict__ Wqb, const __hip_bfloat16* __restrict__ Wkb,
    const __hip_bfloat16* __restrict__ Wvb,
    const float* __restrict__ bq, const float* __restrict__ bk,
    const float* __restrict__ bv,
    const float2* __restrict__ CS,
    __hip_bfloat16* __restrict__ Qo, __hip_bfloat16* __restrict__ Ko,
    __hip_bfloat16* __restrict__ Vo)
{
    __shared__ __hip_bfloat16 Xs[128 * 64];
    __shared__ __hip_bfloat16 Ws[128 * 64];
    const int tid  = threadIdx.x;
    const int w    = tid >> 6, lane = tid & 63;
    const int lrow = lane & 15, lhi = lane >> 4;
    const int L    = blockIdx.x;
    const int xcd  = L & 7, slot = L >> 3;
    const int wq   = slot >> 2, ms = slot & 3;
    const int pj   = wq >> 3;                    // 0=Q 1=K 2=V (wave-uniform)
    const int n0   = (wq & 7) * 128;
    const int m0   = (xcd + 8 * ms) * 128;
    const int rm   = (w & 1) * 64;
    const int rn   = (w >> 1) * 64;
    const int srow = lane >> 3, scb = lane & 7;

    const __hip_bfloat16* Wb   = (pj == 0) ? Wqb : (pj == 1) ? Wkb : Wvb;
    const float*          bias = (pj == 0) ? bq : (pj == 1) ? bk : bv;

    f32x4 acc[16];
#pragma unroll
    for (int i = 0; i < 16; i++) acc[i] = (f32x4){0.f, 0.f, 0.f, 0.f};

    for (int k0 = 0; k0 < Dn; k0 += 64) {
#pragma unroll
        for (int j = 0; j < 4; j++) {
            const int row = w * 32 + j * 8 + srow;
            const int sc  = ((scb ^ (row & 7)) << 3);
            g2l16(X  + (size_t)(m0 + row) * Dn + k0 + sc, &Xs[(w * 32 + j * 8) * 64]);
            g2l16(Wb + (size_t)(n0 + row) * Dn + k0 + sc, &Ws[(w * 32 + j * 8) * 64]);
        }
        __syncthreads();

#pragma unroll
        for (int ksub = 0; ksub < 2; ksub++) {
            bf16x8 FX[4], FW[4];
#pragma unroll
            for (int t = 0; t < 4; t++) {
                const int ra = rm + t * 16 + lrow;
                FX[t] = *(const bf16x8*)&Xs[ra * 64 + (((ksub * 4 + lhi) ^ (ra & 7)) << 3)];
                const int rb = rn + t * 16 + lrow;
                FW[t] = *(const bf16x8*)&Ws[rb * 64 + (((ksub * 4 + lhi) ^ (rb & 7)) << 3)];
            }
            if (pj == 2) {
#pragma unroll
                for (int tm = 0; tm < 4; tm++)
#pragma unroll
                    for (int tn = 0; tn < 4; tn++)
                        acc[tm * 4 + tn] = __builtin_amdgcn_mfma_f32_16x16x32_bf16(
                            FX[tm], FW[tn], acc[tm * 4 + tn], 0, 0, 0);
            } else {
#pragma unroll
                for (int tn = 0; tn < 4; tn++)
#pragma unroll
                    for (int tm = 0; tm < 4; tm++)
                        acc[tn * 4 + tm] = __builtin_amdgcn_mfma_f32_16x16x32_bf16(
                            FW[tn], FX[tm], acc[tn * 4 + tm], 0, 0, 0);
            }
        }
        __syncthreads();
    }

    const int h = (n0 >> 6) + (w >> 1);

    if (pj != 2) {
        __hip_bfloat16* outb = (pj == 0) ? Qo : Ko;
        const float SCL = 0.125f * LOG2E;
#pragma unroll
        for (int tn = 0; tn < 4; tn++) {
            const int hd0 = tn * 16 + lhi * 4;
            const float4 b4 = *(const float4*)&bias[n0 + rn + hd0];
#pragma unroll
            for (int tm = 0; tm < 4; tm++) {
                const int m = m0 + rm + tm * 16 + lrow;
                const int s = m & (Sn - 1), bb = m >> 11;
                f32x4 a = acc[tn * 4 + tm];
                float v0 = a[0] + b4.x, v1 = a[1] + b4.y;
                float v2 = a[2] + b4.z, v3 = a[3] + b4.w;
                if (pj == 0) { v0 *= SCL; v1 *= SCL; v2 *= SCL; v3 *= SCL; }
                const float4 cs01 = *(const float4*)&CS[(size_t)s * 64 + hd0];
                const float4 cs23 = *(const float4*)&CS[(size_t)s * 64 + hd0 + 2];
                const float r0 = v0 * cs01.x - v1 * cs01.y;  // rot[2i]   = -t[2i+1]
                const float r1 = v1 * cs01.z + v0 * cs01.w;  // rot[2i+1] =  t[2i]
                const float r2 = v2 * cs23.x - v3 * cs23.y;
                const float r3 = v3 * cs23.z + v2 * cs23.w;
                *(uint2*)(outb + ((size_t)(bb * Hn + h) * Sn + s) * HDn + hd0) =
                    pack4bf(r0, r1, r2, r3);
            }
        }
    } else {
#pragma unroll
        for (int tn = 0; tn < 4; tn++) {
            const int c = tn * 16 + lrow;
            const float bc = bias[n0 + rn + c];
#pragma unroll
            for (int tm = 0; tm < 4; tm++) {
                const int mb = m0 + rm + tm * 16 + lhi * 4;
                const int s = mb & (Sn - 1), bb = mb >> 11;
                f32x4 a = acc[tm * 4 + tn];
                *(uint2*)(Vo + ((size_t)(bb * Hn + h) * HDn + c) * Sn + s) =
                    pack4bf(a[0] + bc, a[1] + bc, a[2] + bc, a[3] + bc);
            }
        }
    }
}

// ---------------------------------------------------------------------------
// O projection: out = A @ Wo^T + bo + resid, fp32 [m][n].
// ---------------------------------------------------------------------------
__global__ __launch_bounds__(256) void o_proj(
    const __hip_bfloat16* __restrict__ X,
    const __hip_bfloat16* __restrict__ Wb,
    const float* __restrict__ bias,
    const float* __restrict__ resid,
    float* __restrict__ outf)
{
    __shared__ __hip_bfloat16 Xs[128 * 64];
    __shared__ __hip_bfloat16 Ws[128 * 64];
    const int tid  = threadIdx.x;
    const int w    = tid >> 6, lane = tid & 63;
    const int lrow = lane & 15, lhi = lane >> 4;
    const int L    = blockIdx.x;
    const int xcd  = L & 7, slot = L >> 3;
    const int n0   = (slot >> 2) * 128;
    const int m0   = (xcd + 8 * (slot & 3)) * 128;
    const int rm   = (w & 1) * 64;
    const int rn   = (w >> 1) * 64;
    const int srow = lane >> 3, scb = lane & 7;

    f32x4 acc[16];
#pragma unroll
    for (int i = 0; i < 16; i++) acc[i] = (f32x4){0.f, 0.f, 0.f, 0.f};

    for (int k0 = 0; k0 < Dn; k0 += 64) {
#pragma unroll
        for (int j = 0; j < 4; j++) {
            const int row = w * 32 + j * 8 + srow;
            const int sc  = ((scb ^ (row & 7)) << 3);
            g2l16(X  + (size_t)(m0 + row) * Dn + k0 + sc, &Xs[(w * 32 + j * 8) * 64]);
            g2l16(Wb + (size_t)(n0 + row) * Dn + k0 + sc, &Ws[(w * 32 + j * 8) * 64]);
        }
        __syncthreads();

#pragma unroll
        for (int ksub = 0; ksub < 2; ksub++) {
            bf16x8 FX[4], FW[4];
#pragma unroll
            for (int t = 0; t < 4; t++) {
                const int ra = rm + t * 16 + lrow;
                FX[t] = *(const bf16x8*)&Xs[ra * 64 + (((ksub * 4 + lhi) ^ (ra & 7)) << 3)];
                const int rb = rn + t * 16 + lrow;
                FW[t] = *(const bf16x8*)&Ws[rb * 64 + (((ksub * 4 + lhi) ^ (rb & 7)) << 3)];
            }
#pragma unroll
            for (int tn = 0; tn < 4; tn++)
#pragma unroll
                for (int tm = 0; tm < 4; tm++)
                    acc[tn * 4 + tm] = __builtin_amdgcn_mfma_f32_16x16x32_bf16(
                        FW[tn], FX[tm], acc[tn * 4 + tm], 0, 0, 0);
        }
        __syncthreads();
    }

#pragma unroll
    for (int tn = 0; tn < 4; tn++) {
        const int nb = n0 + rn + tn * 16 + lhi * 4;
        const float4 b4 = *(const float4*)&bias[nb];
#pragma unroll
        for (int tm = 0; tm < 4; tm++) {
            const int m = m0 + rm + tm * 16 + lrow;
            f32x4 a = acc[tn * 4 + tm];
            const float4 rr = *(const float4*)&resid[(size_t)m * Dn + nb];
            *(float4*)(outf + (size_t)m * Dn + nb) =
                make_float4(a[0] + b4.x + rr.x, a[1] + b4.y + rr.y,
                            a[2] + b4.z + rr.z, a[3] + b4.w + rr.w);
        }
    }
}

// ---------------------------------------------------------------------------
// Flash attention, parameterized by q_base so it can run as 4 dispatches of
// 256 blocks (measurement: frees top-5 profile slots for the other kernels).
// ---------------------------------------------------------------------------
struct __align__(16) TileBuf {
    __hip_bfloat16 K[64 * 64];   // [k-local][hd]          8 KB
    __hip_bfloat16 V[64 * 64];   // [hd][k-local]          8 KB
    float          M[64 * 64];   // [q-local][k-local]    16 KB
};

__device__ __forceinline__ void stage_tiles(
    TileBuf& t,
    const __hip_bfloat16* __restrict__ Kb,
    const __hip_bfloat16* __restrict__ Vb,
    const float* __restrict__ Mq0,
    int k0, int w, int lane)
{
#pragma unroll
    for (int j = 0; j < 2; j++) {
        const int row = w * 16 + j * 8 + (lane >> 3);
        const int blk = (lane & 7) ^ (row & 7);
        g2l16(Kb + (size_t)(k0 + row) * HDn + blk * 8, &t.K[(w * 16 + j * 8) * 64]);
        g2l16(Vb + (size_t)row * Sn + k0 + blk * 8,    &t.V[(w * 16 + j * 8) * 64]);
    }
#pragma unroll
    for (int j = 0; j < 4; j++) {
        const int row = w * 16 + j * 4 + (lane >> 4);
        const int blk = (lane & 15) ^ (row & 7);
        g2l16(Mq0 + (size_t)row * Sn + k0 + blk * 4,   &t.M[(w * 16 + j * 4) * 64]);
    }
}

__global__ __launch_bounds__(256) void attn_kernel(
    const __hip_bfloat16* __restrict__ Q,   // [bh][s][hd], prescaled 0.125*log2e
    const __hip_bfloat16* __restrict__ K,   // [bh][s][hd]
    const __hip_bfloat16* __restrict__ Vt,  // [bh][hd][s]
    const float* __restrict__ mask,         // [b][q][k] fp32 (raw input)
    const float* __restrict__ cwp,
    __hip_bfloat16* __restrict__ A,         // [b*S+q][D] bf16
    int q_base)
{
    __shared__ TileBuf tb[2];               // 64 KB
    const int tid  = threadIdx.x;
    const int w    = tid >> 6, lane = tid & 63;
    const int lrow = lane & 15, lhi = lane >> 4;
    const int L    = blockIdx.x;            // 0..255
    const int xcd  = L & 7, slot = L >> 3;  // slot 0..31
    const int b    = xcd >> 2;
    const int h    = (xcd & 3) * 4 + (slot & 3);
    const int q0   = q_base + (slot >> 2) * 64;   // 8 q-tiles per dispatch
    const int bh   = b * Hn + h;
    const int q    = q0 + w * 16 + lrow;
    const float cwl = cwp[0] * LOG2E;

    const __hip_bfloat16* Qp  = Q + ((size_t)bh * Sn + q) * HDn + lhi * 8;
    const bf16x8 Qf0 = *(const bf16x8*)(Qp);
    const bf16x8 Qf1 = *(const bf16x8*)(Qp + 32);
    const __hip_bfloat16* Kb  = K  + (size_t)bh * Sn * HDn;
    const __hip_bfloat16* Vb  = Vt + (size_t)bh * HDn * Sn;
    const float*          Mq0 = mask + ((size_t)b * Sn + q0) * Sn;

    f32x4 Oc[4];
#pragma unroll
    for (int i = 0; i < 4; i++) Oc[i] = (f32x4){0.f, 0.f, 0.f, 0.f};
    float lsum = 0.f;

    stage_tiles(tb[0], Kb, Vb, Mq0, 0, w, lane);
    __syncthreads();

    for (int it = 0; it < Sn / 64; it++) {
        const int k0 = it * 64;
        if (it + 1 < Sn / 64)
            stage_tiles(tb[(it + 1) & 1], Kb, Vb, Mq0, k0 + 64, w, lane);
        const TileBuf& t = tb[it & 1];

        f32x4 st[4];
#pragma unroll
        for (int kt = 0; kt < 4; kt++) {
            const int rl = kt * 16 + lrow;
            const bf16x8 ka = *(const bf16x8*)&t.K[rl * 64 + ((lhi       ^ (rl & 7)) * 8)];
            const bf16x8 kc = *(const bf16x8*)&t.K[rl * 64 + (((4 + lhi) ^ (rl & 7)) * 8)];
            f32x4 z = (f32x4){0.f, 0.f, 0.f, 0.f};
            z = __builtin_amdgcn_mfma_f32_16x16x32_bf16(ka, Qf0, z, 0, 0, 0);
            z = __builtin_amdgcn_mfma_f32_16x16x32_bf16(kc, Qf1, z, 0, 0, 0);
            st[kt] = z;
        }

        const int rq = w * 16 + lrow;
        bf16x4 pk[4];
#pragma unroll
        for (int kt = 0; kt < 4; kt++) {
            const int mb = (kt * 4 + lhi) ^ (rq & 7);
            const f32x4 mf = *(const f32x4*)&t.M[rq * 64 + mb * 4];
            const float p0 = fexp2(fmaf(mf[0], cwl, st[kt][0]));
            const float p1 = fexp2(fmaf(mf[1], cwl, st[kt][1]));
            const float p2 = fexp2(fmaf(mf[2], cwl, st[kt][2]));
            const float p3 = fexp2(fmaf(mf[3], cwl, st[kt][3]));
            lsum += (p0 + p1) + (p2 + p3);
            pk[kt] = pack4bfv(p0, p1, p2, p3);
        }

#pragma unroll
        for (int ch = 0; ch < 4; ch++) {
            const int rv = ch * 16 + lrow;
#pragma unroll
            for (int kt = 0; kt < 4; kt++) {
                const int eo = (((2 * kt + (lhi >> 1)) ^ (rv & 7)) * 8) + (lhi & 1) * 4;
                const bf16x4 vf = *(const bf16x4*)&t.V[rv * 64 + eo];
                Oc[ch] = __builtin_amdgcn_mfma_f32_16x16x16bf16_1k(
                    vf, pk[kt], Oc[ch], 0, 0, 0);
            }
        }
        __syncthreads();
    }

    lsum += __shfl_xor(lsum, 16, 64);
    lsum += __shfl_xor(lsum, 32, 64);
    const float inv = 1.f / lsum;

    __hip_bfloat16* ap = A + ((size_t)(b * Sn + q)) * Dn + h * HDn;
#pragma unroll
    for (int ch = 0; ch < 4; ch++) {
        *(uint2*)(ap + ch * 16 + lhi * 4) =
            pack4bf(Oc[ch][0] * inv, Oc[ch][1] * inv, Oc[ch][2] * inv, Oc[ch][3] * inv);
    }
}

// ---------------------------------------------------------------------------
// LayerNorm over D=1024 per row; single pass (sum + sumsq), 1 barrier.
// ---------------------------------------------------------------------------
__global__ __launch_bounds__(256) void ln_kernel(
    const float* __restrict__ Yin, const float* __restrict__ gamma,
    const float* __restrict__ beta, float* __restrict__ out)
{
    __shared__ float2 wred[4];
    const int m   = blockIdx.x;
    const int tid = threadIdx.x;
    const size_t base = (size_t)m * Dn + tid * 4;
    float4 y = *(const float4*)(Yin + base);

    float s1 = y.x + y.y + y.z + y.w;
    float s2 = y.x * y.x + y.y * y.y + y.z * y.z + y.w * y.w;
#pragma unroll
    for (int off = 32; off; off >>= 1) {
        s1 += __shfl_xor(s1, off, 64);
        s2 += __shfl_xor(s2, off, 64);
    }
    if ((tid & 63) == 0) wred[tid >> 6] = make_float2(s1, s2);
    __syncthreads();
    const float S1 = wred[0].x + wred[1].x + wred[2].x + wred[3].x;
    const float S2 = wred[0].y + wred[1].y + wred[2].y + wred[3].y;
    const float mu  = S1 * (1.f / Dn);
    const float var = S2 * (1.f / Dn) - mu * mu;
    const float rin = rsqrtf(var + 1e-5f);

    float4 gv = *(const float4*)(gamma + tid * 4);
    float4 bv = *(const float4*)(beta  + tid * 4);
    *(float4*)(out + base) = make_float4((y.x - mu) * rin * gv.x + bv.x,
                                         (y.y - mu) * rin * gv.y + bv.y,
                                         (y.z - mu) * rin * gv.z + bv.z,
                                         (y.w - mu) * rin * gv.w + bv.w);
}

// ---------------------------------------------------------------------------
extern "C" void kernel_launch(void* const* d_in, const int* in_sizes, int n_in,
                              void* d_out, int out_size, void* d_ws, size_t ws_size,
                              hipStream_t stream)
{
    const float* x     = (const float*)d_in[0];
    const float* mask  = (const float*)d_in[1];
    const float* Wq    = (const float*)d_in[2];
    const float* bq    = (const float*)d_in[3];
    const float* Wk    = (const float*)d_in[4];
    const float* bk    = (const float*)d_in[5];
    const float* Wv    = (const float*)d_in[6];
    const float* bv    = (const float*)d_in[7];
    const float* Wo    = (const float*)d_in[8];
    const float* bo    = (const float*)d_in[9];
    const float* gamma = (const float*)d_in[10];
    const float* beta  = (const float*)d_in[11];
    const float* cw    = (const float*)d_in[12];
    float* out = (float*)d_out;

    const size_t MB = 1024 * 1024;
    char* ws = (char*)d_ws;
    __hip_bfloat16* Xb  = (__hip_bfloat16*)(ws);            // 8 MB (reused as Ab)
    __hip_bfloat16* Qb  = (__hip_bfloat16*)(ws +  8 * MB);  // 8 MB
    __hip_bfloat16* Kb  = (__hip_bfloat16*)(ws + 16 * MB);  // 8 MB
    __hip_bfloat16* Vtb = (__hip_bfloat16*)(ws + 24 * MB);  // 8 MB
    __hip_bfloat16* Wqb = (__hip_bfloat16*)(ws + 32 * MB);  // 2 MB
    __hip_bfloat16* Wkb = (__hip_bfloat16*)(ws + 34 * MB);  // 2 MB
    __hip_bfloat16* Wvb = (__hip_bfloat16*)(ws + 36 * MB);  // 2 MB
    __hip_bfloat16* Wob = (__hip_bfloat16*)(ws + 38 * MB);  // 2 MB
    float2*         CS  = (float2*)        (ws + 40 * MB);  // 1 MB -> 41 MB total
    __hip_bfloat16* Ab  = Xb;  // attn out overlays Xb (dead after V projection)

    prep_kernel<<<8448, 256, 0, stream>>>(x, Wq, Wk, Wv, Wo,
                                          Xb, Wqb, Wkb, Wvb, Wob, CS);
    qkv_proj<<<768, 256, 0, stream>>>(Xb, Wqb, Wkb, Wvb,
                                      bq, bk, bv, CS, Qb, Kb, Vtb);
    // attn as 4 quarter-dispatches (256 blocks each) so any other kernel
    // >~23 us must appear in the top-5 profile with full counters.
    attn_kernel<<<256, 256, 0, stream>>>(Qb, Kb, Vtb, mask, cw, Ab, 0);
    attn_kernel<<<256, 256, 0, stream>>>(Qb, Kb, Vtb, mask, cw, Ab, 512);
    attn_kernel<<<256, 256, 0, stream>>>(Qb, Kb, Vtb, mask, cw, Ab, 1024);
    attn_kernel<<<256, 256, 0, stream>>>(Qb, Kb, Vtb, mask, cw, Ab, 1536);
    o_proj<<<256, 256, 0, stream>>>(Ab, Wob, bo, x, out);
    ln_kernel<<<Bn * Sn, 256, 0, stream>>>(out, gamma, beta, out);
}

// Round 14
// 279.434 us; speedup vs baseline: 1.2483x; 1.2483x over previous
//
#include <hip/hip_runtime.h>
#include <hip/hip_bf16.h>
#include <math.h>

#define Bn  2
#define Sn  2048
#define Dn  1024
#define Hn  16
#define HDn 64

typedef __attribute__((ext_vector_type(8))) short bf16x8;
typedef __attribute__((ext_vector_type(4))) short bf16x4;
typedef __attribute__((ext_vector_type(4))) float f32x4;

#define LOG2E 1.44269504088896340736f

// raw v_exp_f32 (2^x). __exp2f is NOT a HIP intrinsic (glibc macro collision).
__device__ __forceinline__ float fexp2(float x) {
    return __builtin_amdgcn_exp2f(x);
}

// packed f32x2 -> bf16x2 converts (v_cvt_pk_bf16_f32 on gfx950)
__device__ __forceinline__ uint2 pack4bf(float a, float b, float c, float d) {
    union { __hip_bfloat162 h2[2]; uint2 u; } p;
    p.h2[0] = __float22bfloat162_rn(make_float2(a, b));
    p.h2[1] = __float22bfloat162_rn(make_float2(c, d));
    return p.u;
}

__device__ __forceinline__ bf16x4 pack4bfv(float a, float b, float c, float d) {
    union { __hip_bfloat162 h2[2]; bf16x4 v; } p;
    p.h2[0] = __float22bfloat162_rn(make_float2(a, b));
    p.h2[1] = __float22bfloat162_rn(make_float2(c, d));
    return p.v;
}

// async global->LDS, 16B per lane. lbase must be wave-uniform; g is per-lane.
__device__ __forceinline__ void g2l16(const void* g, void* lbase) {
    __builtin_amdgcn_global_load_lds(
        (const __attribute__((address_space(1))) void*)g,
        (__attribute__((address_space(3))) void*)lbase, 16, 0, 0);
}

// ---------------------------------------------------------------------------
// Fused prep: casts x + 4 weights to bf16, and builds the RoPE cos/sin table.
// ---------------------------------------------------------------------------
__global__ __launch_bounds__(256) void prep_kernel(
    const float* __restrict__ x,
    const float* __restrict__ Wq, const float* __restrict__ Wk,
    const float* __restrict__ Wv, const float* __restrict__ Wo,
    __hip_bfloat16* __restrict__ Xb,
    __hip_bfloat16* __restrict__ Wqb, __hip_bfloat16* __restrict__ Wkb,
    __hip_bfloat16* __restrict__ Wvb, __hip_bfloat16* __restrict__ Wob,
    float2* __restrict__ CS)
{
    const int bx = blockIdx.x, tid = threadIdx.x;
    if (bx < 4096) {
        const size_t i = (size_t)bx * 1024 + tid * 4;
        float4 v = *(const float4*)(x + i);
        *(uint2*)(Xb + i) = pack4bf(v.x, v.y, v.z, v.w);
    } else if (bx < 8192) {
        const int r = bx - 4096;
        const int which = r >> 10;
        const size_t i = (size_t)(r & 1023) * 1024 + tid * 4;
        const float* s = (which == 0) ? Wq : (which == 1) ? Wk : (which == 2) ? Wv : Wo;
        __hip_bfloat16* d = (which == 0) ? Wqb : (which == 1) ? Wkb : (which == 2) ? Wvb : Wob;
        float4 v = *(const float4*)(s + i);
        *(uint2*)(d + i) = pack4bf(v.x, v.y, v.z, v.w);
    } else {
        const float NEG_L2C = -0.41524101186092033f;   // -log2(10000)/32
        const int idx = ((bx - 8192) * 256 + tid) * 2;  // even
        const int s = idx >> 6, d0 = idx & 63;
        const float sf = (float)s;
        const float f0 = exp2f((float)(d0 & 31) * NEG_L2C);
        const float f1 = exp2f((float)((d0 + 1) & 31) * NEG_L2C);
        *(float4*)(&CS[(size_t)s * 64 + d0]) =
            make_float4(__cosf(sf * f0), __sinf(sf * f0),
                        __cosf(sf * f1), __sinf(sf * f1));
    }
}

// ---------------------------------------------------------------------------
// Fused Q/K/V projection GEMM. XCD-swizzled 1-D grid (768 blocks).
// 128x128 tile, BK=64, 32 KB LDS, 2x2 wave grid. (Measured R13: 63 us,
// above the m97 shape-curve for K=1024 — near this structure's plateau.)
// ---------------------------------------------------------------------------
__global__ __launch_bounds__(256) void qkv_proj(
    const __hip_bfloat16* __restrict__ X,
    const __hip_bfloat16* __restrict__ Wqb, const __hip_bfloat16* __restrict__ Wkb,
    const __hip_bfloat16* __restrict__ Wvb,
    const float* __restrict__ bq, const float* __restrict__ bk,
    const float* __restrict__ bv,
    const float2* __restrict__ CS,
    __hip_bfloat16* __restrict__ Qo, __hip_bfloat16* __restrict__ Ko,
    __hip_bfloat16* __restrict__ Vo)
{
    __shared__ __hip_bfloat16 Xs[128 * 64];
    __shared__ __hip_bfloat16 Ws[128 * 64];
    const int tid  = threadIdx.x;
    const int w    = tid >> 6, lane = tid & 63;
    const int lrow = lane & 15, lhi = lane >> 4;
    const int L    = blockIdx.x;
    const int xcd  = L & 7, slot = L >> 3;
    const int wq   = slot >> 2, ms = slot & 3;
    const int pj   = wq >> 3;                    // 0=Q 1=K 2=V (wave-uniform)
    const int n0   = (wq & 7) * 128;
    const int m0   = (xcd + 8 * ms) * 128;
    const int rm   = (w & 1) * 64;
    const int rn   = (w >> 1) * 64;
    const int srow = lane >> 3, scb = lane & 7;

    const __hip_bfloat16* Wb   = (pj == 0) ? Wqb : (pj == 1) ? Wkb : Wvb;
    const float*          bias = (pj == 0) ? bq : (pj == 1) ? bk : bv;

    f32x4 acc[16];
#pragma unroll
    for (int i = 0; i < 16; i++) acc[i] = (f32x4){0.f, 0.f, 0.f, 0.f};

    for (int k0 = 0; k0 < Dn; k0 += 64) {
#pragma unroll
        for (int j = 0; j < 4; j++) {
            const int row = w * 32 + j * 8 + srow;
            const int sc  = ((scb ^ (row & 7)) << 3);
            g2l16(X  + (size_t)(m0 + row) * Dn + k0 + sc, &Xs[(w * 32 + j * 8) * 64]);
            g2l16(Wb + (size_t)(n0 + row) * Dn + k0 + sc, &Ws[(w * 32 + j * 8) * 64]);
        }
        __syncthreads();

#pragma unroll
        for (int ksub = 0; ksub < 2; ksub++) {
            bf16x8 FX[4], FW[4];
#pragma unroll
            for (int t = 0; t < 4; t++) {
                const int ra = rm + t * 16 + lrow;
                FX[t] = *(const bf16x8*)&Xs[ra * 64 + (((ksub * 4 + lhi) ^ (ra & 7)) << 3)];
                const int rb = rn + t * 16 + lrow;
                FW[t] = *(const bf16x8*)&Ws[rb * 64 + (((ksub * 4 + lhi) ^ (rb & 7)) << 3)];
            }
            if (pj == 2) {
#pragma unroll
                for (int tm = 0; tm < 4; tm++)
#pragma unroll
                    for (int tn = 0; tn < 4; tn++)
                        acc[tm * 4 + tn] = __builtin_amdgcn_mfma_f32_16x16x32_bf16(
                            FX[tm], FW[tn], acc[tm * 4 + tn], 0, 0, 0);
            } else {
#pragma unroll
                for (int tn = 0; tn < 4; tn++)
#pragma unroll
                    for (int tm = 0; tm < 4; tm++)
                        acc[tn * 4 + tm] = __builtin_amdgcn_mfma_f32_16x16x32_bf16(
                            FW[tn], FX[tm], acc[tn * 4 + tm], 0, 0, 0);
            }
        }
        __syncthreads();
    }

    const int h = (n0 >> 6) + (w >> 1);

    if (pj != 2) {
        __hip_bfloat16* outb = (pj == 0) ? Qo : Ko;
        const float SCL = 0.125f * LOG2E;
#pragma unroll
        for (int tn = 0; tn < 4; tn++) {
            const int hd0 = tn * 16 + lhi * 4;
            const float4 b4 = *(const float4*)&bias[n0 + rn + hd0];
#pragma unroll
            for (int tm = 0; tm < 4; tm++) {
                const int m = m0 + rm + tm * 16 + lrow;
                const int s = m & (Sn - 1), bb = m >> 11;
                f32x4 a = acc[tn * 4 + tm];
                float v0 = a[0] + b4.x, v1 = a[1] + b4.y;
                float v2 = a[2] + b4.z, v3 = a[3] + b4.w;
                if (pj == 0) { v0 *= SCL; v1 *= SCL; v2 *= SCL; v3 *= SCL; }
                const float4 cs01 = *(const float4*)&CS[(size_t)s * 64 + hd0];
                const float4 cs23 = *(const float4*)&CS[(size_t)s * 64 + hd0 + 2];
                const float r0 = v0 * cs01.x - v1 * cs01.y;  // rot[2i]   = -t[2i+1]
                const float r1 = v1 * cs01.z + v0 * cs01.w;  // rot[2i+1] =  t[2i]
                const float r2 = v2 * cs23.x - v3 * cs23.y;
                const float r3 = v3 * cs23.z + v2 * cs23.w;
                *(uint2*)(outb + ((size_t)(bb * Hn + h) * Sn + s) * HDn + hd0) =
                    pack4bf(r0, r1, r2, r3);
            }
        }
    } else {
#pragma unroll
        for (int tn = 0; tn < 4; tn++) {
            const int c = tn * 16 + lrow;
            const float bc = bias[n0 + rn + c];
#pragma unroll
            for (int tm = 0; tm < 4; tm++) {
                const int mb = m0 + rm + tm * 16 + lhi * 4;
                const int s = mb & (Sn - 1), bb = mb >> 11;
                f32x4 a = acc[tm * 4 + tn];
                *(uint2*)(Vo + ((size_t)(bb * Hn + h) * HDn + c) * Sn + s) =
                    pack4bf(a[0] + bc, a[1] + bc, a[2] + bc, a[3] + bc);
            }
        }
    }
}

// ---------------------------------------------------------------------------
// O projection, SPLIT-K=2: 512 blocks (2/CU co-residency, half the serial
// K-chain each — R13 showed co-residency is the dominant lever). Block ks
// computes K range [ks*512, ks*512+512). ks=0 adds bias+resid; partials go
// to opart[ks]; ln_kernel fuses the final add.
// ---------------------------------------------------------------------------
__global__ __launch_bounds__(256) void o_proj(
    const __hip_bfloat16* __restrict__ X,
    const __hip_bfloat16* __restrict__ Wb,
    const float* __restrict__ bias,
    const float* __restrict__ resid,
    float* __restrict__ opart)              // [2][4096][1024]
{
    __shared__ __hip_bfloat16 Xs[128 * 64];
    __shared__ __hip_bfloat16 Ws[128 * 64];
    const int tid  = threadIdx.x;
    const int w    = tid >> 6, lane = tid & 63;
    const int lrow = lane & 15, lhi = lane >> 4;
    const int L    = blockIdx.x;             // 0..511
    const int xcd  = L & 7, slot = L >> 3;   // slot 0..63
    const int m0   = (xcd + 8 * (slot & 3)) * 128;
    const int n0   = ((slot >> 2) & 7) * 128;
    const int ks   = slot >> 5;              // 0 or 1
    const int kbeg = ks * 512;
    const int rm   = (w & 1) * 64;
    const int rn   = (w >> 1) * 64;
    const int srow = lane >> 3, scb = lane & 7;

    f32x4 acc[16];
#pragma unroll
    for (int i = 0; i < 16; i++) acc[i] = (f32x4){0.f, 0.f, 0.f, 0.f};

    for (int k0 = kbeg; k0 < kbeg + 512; k0 += 64) {
#pragma unroll
        for (int j = 0; j < 4; j++) {
            const int row = w * 32 + j * 8 + srow;
            const int sc  = ((scb ^ (row & 7)) << 3);
            g2l16(X  + (size_t)(m0 + row) * Dn + k0 + sc, &Xs[(w * 32 + j * 8) * 64]);
            g2l16(Wb + (size_t)(n0 + row) * Dn + k0 + sc, &Ws[(w * 32 + j * 8) * 64]);
        }
        __syncthreads();

#pragma unroll
        for (int ksub = 0; ksub < 2; ksub++) {
            bf16x8 FX[4], FW[4];
#pragma unroll
            for (int t = 0; t < 4; t++) {
                const int ra = rm + t * 16 + lrow;
                FX[t] = *(const bf16x8*)&Xs[ra * 64 + (((ksub * 4 + lhi) ^ (ra & 7)) << 3)];
                const int rb = rn + t * 16 + lrow;
                FW[t] = *(const bf16x8*)&Ws[rb * 64 + (((ksub * 4 + lhi) ^ (rb & 7)) << 3)];
            }
#pragma unroll
            for (int tn = 0; tn < 4; tn++)
#pragma unroll
                for (int tm = 0; tm < 4; tm++)
                    acc[tn * 4 + tm] = __builtin_amdgcn_mfma_f32_16x16x32_bf16(
                        FW[tn], FX[tm], acc[tn * 4 + tm], 0, 0, 0);
        }
        __syncthreads();
    }

    float* outp = opart + (size_t)ks * Bn * Sn * Dn;
#pragma unroll
    for (int tn = 0; tn < 4; tn++) {
        const int nb = n0 + rn + tn * 16 + lhi * 4;
        float4 b4 = make_float4(0.f, 0.f, 0.f, 0.f);
        if (ks == 0) b4 = *(const float4*)&bias[nb];
#pragma unroll
        for (int tm = 0; tm < 4; tm++) {
            const int m = m0 + rm + tm * 16 + lrow;
            f32x4 a = acc[tn * 4 + tm];
            float4 o = make_float4(a[0] + b4.x, a[1] + b4.y, a[2] + b4.z, a[3] + b4.w);
            if (ks == 0) {
                const float4 rr = *(const float4*)&resid[(size_t)m * Dn + nb];
                o.x += rr.x; o.y += rr.y; o.z += rr.z; o.w += rr.w;
            }
            *(float4*)(outp + (size_t)m * Dn + nb) = o;
        }
    }
}

// ---------------------------------------------------------------------------
// Flash attention: LDS-staged double-buffered tiles; fp32 mask read directly.
// Softmax denominator via MFMA: Sc += ones(16x16) . P  — every D row equals
// sum_k P[k][q], and lane's C/D col (lane&15) == its q, so lsum = Sc[0] with
// ZERO VALU adds and ZERO shuffles. XCD-swizzled, single 1024-block dispatch.
// ---------------------------------------------------------------------------
struct __align__(16) TileBuf {
    __hip_bfloat16 K[64 * 64];   // [k-local][hd]          8 KB
    __hip_bfloat16 V[64 * 64];   // [hd][k-local]          8 KB
    float          M[64 * 64];   // [q-local][k-local]    16 KB
};

__device__ __forceinline__ void stage_tiles(
    TileBuf& t,
    const __hip_bfloat16* __restrict__ Kb,
    const __hip_bfloat16* __restrict__ Vb,
    const float* __restrict__ Mq0,
    int k0, int w, int lane)
{
#pragma unroll
    for (int j = 0; j < 2; j++) {
        const int row = w * 16 + j * 8 + (lane >> 3);
        const int blk = (lane & 7) ^ (row & 7);
        g2l16(Kb + (size_t)(k0 + row) * HDn + blk * 8, &t.K[(w * 16 + j * 8) * 64]);
        g2l16(Vb + (size_t)row * Sn + k0 + blk * 8,    &t.V[(w * 16 + j * 8) * 64]);
    }
#pragma unroll
    for (int j = 0; j < 4; j++) {
        const int row = w * 16 + j * 4 + (lane >> 4);
        const int blk = (lane & 15) ^ (row & 7);
        g2l16(Mq0 + (size_t)row * Sn + k0 + blk * 4,   &t.M[(w * 16 + j * 4) * 64]);
    }
}

__global__ __launch_bounds__(256) void attn_kernel(
    const __hip_bfloat16* __restrict__ Q,   // [bh][s][hd], prescaled 0.125*log2e
    const __hip_bfloat16* __restrict__ K,   // [bh][s][hd]
    const __hip_bfloat16* __restrict__ Vt,  // [bh][hd][s]
    const float* __restrict__ mask,         // [b][q][k] fp32 (raw input)
    const float* __restrict__ cwp,
    __hip_bfloat16* __restrict__ A)         // [b*S+q][D] bf16
{
    __shared__ TileBuf tb[2];               // 64 KB
    const int tid  = threadIdx.x;
    const int w    = tid >> 6, lane = tid & 63;
    const int lrow = lane & 15, lhi = lane >> 4;
    const int L    = blockIdx.x;
    const int xcd  = L & 7, slot = L >> 3;
    const int b    = xcd >> 2;
    const int h    = (xcd & 3) * 4 + (slot & 3);
    const int q0   = (slot >> 2) * 64;
    const int bh   = b * Hn + h;
    const int q    = q0 + w * 16 + lrow;
    const float cwl = cwp[0] * LOG2E;

    // A-operand frag of all bf16 1.0 (x16 layout: A[m=lane&15][k=lhi*4+j])
    const short ONE = (short)0x3F80;
    const bf16x4 ones = (bf16x4){ONE, ONE, ONE, ONE};

    const __hip_bfloat16* Qp  = Q + ((size_t)bh * Sn + q) * HDn + lhi * 8;
    const bf16x8 Qf0 = *(const bf16x8*)(Qp);
    const bf16x8 Qf1 = *(const bf16x8*)(Qp + 32);
    const __hip_bfloat16* Kb  = K  + (size_t)bh * Sn * HDn;
    const __hip_bfloat16* Vb  = Vt + (size_t)bh * HDn * Sn;
    const float*          Mq0 = mask + ((size_t)b * Sn + q0) * Sn;

    f32x4 Oc[4];
#pragma unroll
    for (int i = 0; i < 4; i++) Oc[i] = (f32x4){0.f, 0.f, 0.f, 0.f};
    f32x4 Sc = (f32x4){0.f, 0.f, 0.f, 0.f};   // denominator accumulator

    stage_tiles(tb[0], Kb, Vb, Mq0, 0, w, lane);
    __syncthreads();

    for (int it = 0; it < Sn / 64; it++) {
        const int k0 = it * 64;
        if (it + 1 < Sn / 64)
            stage_tiles(tb[(it + 1) & 1], Kb, Vb, Mq0, k0 + 64, w, lane);
        const TileBuf& t = tb[it & 1];

        f32x4 st[4];
#pragma unroll
        for (int kt = 0; kt < 4; kt++) {
            const int rl = kt * 16 + lrow;
            const bf16x8 ka = *(const bf16x8*)&t.K[rl * 64 + ((lhi       ^ (rl & 7)) * 8)];
            const bf16x8 kc = *(const bf16x8*)&t.K[rl * 64 + (((4 + lhi) ^ (rl & 7)) * 8)];
            f32x4 z = (f32x4){0.f, 0.f, 0.f, 0.f};
            z = __builtin_amdgcn_mfma_f32_16x16x32_bf16(ka, Qf0, z, 0, 0, 0);
            z = __builtin_amdgcn_mfma_f32_16x16x32_bf16(kc, Qf1, z, 0, 0, 0);
            st[kt] = z;
        }

        const int rq = w * 16 + lrow;
        bf16x4 pk[4];
#pragma unroll
        for (int kt = 0; kt < 4; kt++) {
            const int mb = (kt * 4 + lhi) ^ (rq & 7);
            const f32x4 mf = *(const f32x4*)&t.M[rq * 64 + mb * 4];
            const float p0 = fexp2(fmaf(mf[0], cwl, st[kt][0]));
            const float p1 = fexp2(fmaf(mf[1], cwl, st[kt][1]));
            const float p2 = fexp2(fmaf(mf[2], cwl, st[kt][2]));
            const float p3 = fexp2(fmaf(mf[3], cwl, st[kt][3]));
            pk[kt] = pack4bfv(p0, p1, p2, p3);
            Sc = __builtin_amdgcn_mfma_f32_16x16x16bf16_1k(ones, pk[kt], Sc, 0, 0, 0);
        }

#pragma unroll
        for (int ch = 0; ch < 4; ch++) {
            const int rv = ch * 16 + lrow;
#pragma unroll
            for (int kt = 0; kt < 4; kt++) {
                const int eo = (((2 * kt + (lhi >> 1)) ^ (rv & 7)) * 8) + (lhi & 1) * 4;
                const bf16x4 vf = *(const bf16x4*)&t.V[rv * 64 + eo];
                Oc[ch] = __builtin_amdgcn_mfma_f32_16x16x16bf16_1k(
                    vf, pk[kt], Oc[ch], 0, 0, 0);
            }
        }
        __syncthreads();
    }

    const float inv = 1.f / Sc[0];   // all rows of Sc equal l[q]; col = lrow = q

    __hip_bfloat16* ap = A + ((size_t)(b * Sn + q)) * Dn + h * HDn;
#pragma unroll
    for (int ch = 0; ch < 4; ch++) {
        *(uint2*)(ap + ch * 16 + lhi * 4) =
            pack4bf(Oc[ch][0] * inv, Oc[ch][1] * inv, Oc[ch][2] * inv, Oc[ch][3] * inv);
    }
}

// ---------------------------------------------------------------------------
// LayerNorm over D=1024 per row, fusing the o_proj split-K partial add.
// Single pass (sum + sumsq), 1 barrier.
// ---------------------------------------------------------------------------
__global__ __launch_bounds__(256) void ln_kernel(
    const float* __restrict__ Yin0, const float* __restrict__ Yin1,
    const float* __restrict__ gamma, const float* __restrict__ beta,
    float* __restrict__ out)
{
    __shared__ float2 wred[4];
    const int m   = blockIdx.x;
    const int tid = threadIdx.x;
    const size_t base = (size_t)m * Dn + tid * 4;
    float4 y0 = *(const float4*)(Yin0 + base);
    float4 y1 = *(const float4*)(Yin1 + base);
    float4 y = make_float4(y0.x + y1.x, y0.y + y1.y, y0.z + y1.z, y0.w + y1.w);

    float s1 = y.x + y.y + y.z + y.w;
    float s2 = y.x * y.x + y.y * y.y + y.z * y.z + y.w * y.w;
#pragma unroll
    for (int off = 32; off; off >>= 1) {
        s1 += __shfl_xor(s1, off, 64);
        s2 += __shfl_xor(s2, off, 64);
    }
    if ((tid & 63) == 0) wred[tid >> 6] = make_float2(s1, s2);
    __syncthreads();
    const float S1 = wred[0].x + wred[1].x + wred[2].x + wred[3].x;
    const float S2 = wred[0].y + wred[1].y + wred[2].y + wred[3].y;
    const float mu  = S1 * (1.f / Dn);
    const float var = S2 * (1.f / Dn) - mu * mu;
    const float rin = rsqrtf(var + 1e-5f);

    float4 gv = *(const float4*)(gamma + tid * 4);
    float4 bv = *(const float4*)(beta  + tid * 4);
    *(float4*)(out + base) = make_float4((y.x - mu) * rin * gv.x + bv.x,
                                         (y.y - mu) * rin * gv.y + bv.y,
                                         (y.z - mu) * rin * gv.z + bv.z,
                                         (y.w - mu) * rin * gv.w + bv.w);
}

// ---------------------------------------------------------------------------
extern "C" void kernel_launch(void* const* d_in, const int* in_sizes, int n_in,
                              void* d_out, int out_size, void* d_ws, size_t ws_size,
                              hipStream_t stream)
{
    const float* x     = (const float*)d_in[0];
    const float* mask  = (const float*)d_in[1];
    const float* Wq    = (const float*)d_in[2];
    const float* bq    = (const float*)d_in[3];
    const float* Wk    = (const float*)d_in[4];
    const float* bk    = (const float*)d_in[5];
    const float* Wv    = (const float*)d_in[6];
    const float* bv    = (const float*)d_in[7];
    const float* Wo    = (const float*)d_in[8];
    const float* bo    = (const float*)d_in[9];
    const float* gamma = (const float*)d_in[10];
    const float* beta  = (const float*)d_in[11];
    const float* cw    = (const float*)d_in[12];
    float* out = (float*)d_out;

    const size_t MB = 1024 * 1024;
    char* ws = (char*)d_ws;
    // Layout (49 MB total). opart overlays Qb/Kb/Vtb (dead after attn).
    __hip_bfloat16* Xb  = (__hip_bfloat16*)(ws);            //  0- 8 MB (also Ab)
    __hip_bfloat16* Wob = (__hip_bfloat16*)(ws +  8 * MB);  //  8-10
    __hip_bfloat16* Wqb = (__hip_bfloat16*)(ws + 10 * MB);  // 10-12
    __hip_bfloat16* Wkb = (__hip_bfloat16*)(ws + 12 * MB);  // 12-14
    __hip_bfloat16* Wvb = (__hip_bfloat16*)(ws + 14 * MB);  // 14-16
    float2*         CS  = (float2*)        (ws + 16 * MB);  // 16-17
    __hip_bfloat16* Qb  = (__hip_bfloat16*)(ws + 17 * MB);  // 17-25
    __hip_bfloat16* Kb  = (__hip_bfloat16*)(ws + 25 * MB);  // 25-33
    __hip_bfloat16* Vtb = (__hip_bfloat16*)(ws + 33 * MB);  // 33-41
    float*          opart = (float*)       (ws + 17 * MB);  // 17-49 (overlay)
    __hip_bfloat16* Ab  = Xb;

    prep_kernel<<<8448, 256, 0, stream>>>(x, Wq, Wk, Wv, Wo,
                                          Xb, Wqb, Wkb, Wvb, Wob, CS);
    qkv_proj<<<768, 256, 0, stream>>>(Xb, Wqb, Wkb, Wvb,
                                      bq, bk, bv, CS, Qb, Kb, Vtb);
    attn_kernel<<<1024, 256, 0, stream>>>(Qb, Kb, Vtb, mask, cw, Ab);
    o_proj<<<512, 256, 0, stream>>>(Ab, Wob, bo, x, opart);
    ln_kernel<<<Bn * Sn, 256, 0, stream>>>(opart, opart + (size_t)Bn * Sn * Dn,
                                           gamma, beta, out);
}